// Round 6
// baseline (1744.831 us; speedup 1.0000x reference)
//
#include <hip/hip_runtime.h>
#include <math.h>

namespace {
constexpr int kBL = 16 * 2048;
constexpr int kH = 256;
constexpr int kNOut = 12;
constexpr int kRows = 64;       // rows per block, halves R0=0..31, R1=32..63
constexpr int kThreads = 512;   // 8 waves; wave wv owns H-cols wv*32..+31 (x3 gates)
constexpr int kS = 264;         // LDS row stride in shorts
constexpr int kWhh = 3 * kH * kH;
}

using short8 = __attribute__((ext_vector_type(8))) short;
using f32x4 = __attribute__((ext_vector_type(4))) float;

__device__ inline void bsplit(float v, short& h, short& l) {
  unsigned u = __float_as_uint(v);
  unsigned rh = u + 0x7FFFu + ((u >> 16) & 1u);   // RNE to bf16
  h = (short)(rh >> 16);
  float hf = __uint_as_float(rh & 0xFFFF0000u);
  float r = v - hf;                                // exact residual
  unsigned u2 = __float_as_uint(r);
  unsigned rl = u2 + 0x7FFFu + ((u2 >> 16) & 1u);
  l = (short)(rl >> 16);
}

// split w_hh [768][256] fp32 -> bf16 hi/lo planes in d_ws
__global__ void split_whh_kernel(const float* __restrict__ w,
                                 short* __restrict__ hi, short* __restrict__ lo) {
  const int i = (blockIdx.x * 256 + threadIdx.x) * 4;
  const float4 v = *reinterpret_cast<const float4*>(w + i);
  short4 h4, l4;
  bsplit(v.x, h4.x, l4.x);
  bsplit(v.y, h4.y, l4.y);
  bsplit(v.z, h4.z, l4.z);
  bsplit(v.w, h4.w, l4.w);
  *reinterpret_cast<short4*>(hi + i) = h4;
  *reinterpret_cast<short4*>(lo + i) = l4;
}

#define MFMA(A, B, C) __builtin_amdgcn_mfma_f32_16x16x32_bf16((A), (B), (C), 0, 0, 0)

__global__ __launch_bounds__(kThreads, 2)
void rbq_mfma5_kernel(const float* __restrict__ emb,    // [BL][256]
                      const float* __restrict__ w_ih,   // [768]
                      const float* __restrict__ b_ih,   // [768]
                      const float* __restrict__ b_hh,   // [768]
                      const float* __restrict__ w_out,  // [256]
                      const float* __restrict__ b_out,  // [1]
                      const short* __restrict__ Bh,     // [768][256] bf16 hi
                      const short* __restrict__ Bl,     // [768][256] bf16 lo
                      float* __restrict__ out) {        // [2][BL][12]
  __shared__ short Ah[kRows][kS];   // h_in hi; halves are phase-disjoint
  __shared__ short Al[kRows][kS];   // h_in lo
  __shared__ float osc[kRows][17];  // per-col-block o partials (pad 17)

  const int tid = threadIdx.x;
  const int lane = tid & 63;
  const int wv = __builtin_amdgcn_readfirstlane(tid >> 6);  // 0..7
  const int grp = lane >> 4;
  const int c16 = lane & 15;
  const int row0 = blockIdx.x * kRows;

  // per-lane gate constants per col-tile t (numerics identical to r4/r5)
  float wihr[2], wihz[2], wihn[2], bihr[2], bihz[2], bihn[2];
  float bhhr[2], bhhz[2], bhhn[2], wo[2];
#pragma unroll
  for (int t = 0; t < 2; ++t) {
    const int j = wv * 32 + t * 16 + c16;
    wihr[t] = w_ih[j]; wihz[t] = w_ih[kH + j]; wihn[t] = w_ih[2 * kH + j];
    bihr[t] = b_ih[j]; bihz[t] = b_ih[kH + j]; bihn[t] = b_ih[2 * kH + j];
    bhhr[t] = b_hh[j]; bhhz[t] = b_hh[kH + j]; bhhn[t] = b_hh[2 * kH + j];
    wo[t] = w_out[j];
  }
  const float bo = b_out[0];
  const size_t q_off = (size_t)kBL * kNOut;

  // h_in registers, split per half so all register indexing stays static
  float h_reg0[2][4][2];   // rows 0..31  (mt 0,1)
  float h_reg1[2][4][2];   // rows 32..63 (mt 2,3)
#pragma unroll
  for (int mt = 0; mt < 4; ++mt)
#pragma unroll
    for (int r = 0; r < 4; ++r)
#pragma unroll
      for (int t = 0; t < 2; ++t) {
        const int rl = mt * 16 + grp * 4 + r;
        const int j = wv * 32 + t * 16 + c16;
        const float e = emb[(size_t)(row0 + rl) * kH + j];
        if (mt < 2) h_reg0[mt][r][t] = e; else h_reg1[mt - 2][r][t] = e;
        short hh, hl;
        bsplit(e, hh, hl);
        Ah[rl][j] = hh;
        Al[rl][j] = hl;
      }
  float xqr = 0.0f;   // q feedback for row == lane
  __syncthreads();

  f32x4 accA[2][2][3];  // acc for R0 (rows mt 0,1)
  f32x4 accB[2][2][3];  // acc for R1 (rows mt 2,3)

  // One phase: [finalize o/q for `qlo` half] + interleaved
  // { MFMA build accN over rows mtB0.. } x { gates consuming accC rows mtC0.. }
  auto phase = [&](f32x4 (&accC)[2][2][3], f32x4 (&accN)[2][2][3],
                   float (&hreg)[2][4][2], const int mtC0, const int mtB0,
                   const int qlo, const int outStep, const bool build,
                   const bool gates, const bool fin) {
    if (fin) {
      float s = bo;                       // same order as r4/r5: bo, then 0..15
#pragma unroll
      for (int w2 = 0; w2 < 16; ++w2) s += osc[lane][w2];
      const float qn = s > 0.0f ? 1.0f : -1.0f;
      const bool inh = (lane >> 5) == (qlo >> 5);
      xqr = inh ? qn : xqr;
      if (wv == 0 && inh) {
        const size_t gr = (size_t)(row0 + lane);
        out[gr * kNOut + outStep] = s;
        out[q_off + gr * kNOut + outStep] = qn;
      }
    }
    if (build) {
#pragma unroll
      for (int m2 = 0; m2 < 2; ++m2)
#pragma unroll
        for (int t = 0; t < 2; ++t) {
          accN[m2][t][0] = f32x4{bhhr[t], bhhr[t], bhhr[t], bhhr[t]};
          accN[m2][t][1] = f32x4{bhhz[t], bhhz[t], bhhz[t], bhhz[t]};
          accN[m2][t][2] = f32x4{bhhn[t], bhhn[t], bhhn[t], bhhn[t]};
        }
    }
    float opart[2][4][2];

    auto gate = [&](const int m2, const int r, const int t, const int rl,
                    const float ev) {
      const float x = __shfl(xqr, rl);
      const float ghr = accC[m2][t][0][r];
      const float ghz = accC[m2][t][1][r];
      const float ghn = accC[m2][t][2][r];
      const float gr = fmaf(x, wihr[t], bihr[t]) + ghr;   // r4/r5 exact exprs
      const float gz = fmaf(x, wihz[t], bihz[t]) + ghz;
      const float gni = fmaf(x, wihn[t], bihn[t]);
      const float rg = 1.0f / (1.0f + __expf(-gr));
      const float zg = 1.0f / (1.0f + __expf(-gz));
      const float ta = gni + rg * ghn;
      const float at = fabsf(ta);
      const float et = __expf(-2.0f * at);
      const float th = copysignf((1.0f - et) / (1.0f + et), ta);
      const float hn = fmaf(zg, hreg[m2][r][t] - th, th);  // (1-z)*n + z*h_in
      opart[m2][r][t] = hn * wo[t];
      const float hnext = hn + ev;
      hreg[m2][r][t] = hnext;
      short hh, hl2;
      bsplit(hnext, hh, hl2);
      const int jj = wv * 32 + t * 16 + c16;
      Ah[rl][jj] = hh;
      Al[rl][jj] = hl2;
    };

#pragma unroll
    for (int kc = 0; kc < 8; ++kc) {
      const int ko = kc * 32 + grp * 8;
      const int m2u = kc >> 2, ru = kc & 3;            // this kc's 2 gate units
      const int rlu = (mtC0 + m2u) * 16 + grp * 4 + ru;
      float e0 = 0.f, e1 = 0.f;
      if (gates) {  // issue e loads early; consumed after the MFMA cluster
        e0 = emb[(size_t)(row0 + rlu) * kH + wv * 32 + c16];
        e1 = emb[(size_t)(row0 + rlu) * kH + wv * 32 + 16 + c16];
      }
      short8 ah[2], al[2], bh[2][3], bl[2][3];
      if (build) {
#pragma unroll
        for (int t = 0; t < 2; ++t)
#pragma unroll
          for (int g = 0; g < 3; ++g) {
            const size_t base =
                (size_t)(g * kH + wv * 32 + t * 16 + c16) * kH + ko;
            bh[t][g] = *reinterpret_cast<const short8*>(Bh + base);
            bl[t][g] = *reinterpret_cast<const short8*>(Bl + base);
          }
#pragma unroll
        for (int m2 = 0; m2 < 2; ++m2) {
          ah[m2] = *reinterpret_cast<const short8*>(&Ah[(mtB0 + m2) * 16 + c16][ko]);
          al[m2] = *reinterpret_cast<const short8*>(&Al[(mtB0 + m2) * 16 + c16][ko]);
        }
        // cluster t=0 (per-acc order hh,lh,hl — identical to r2/r4/r5)
#pragma unroll
        for (int m2 = 0; m2 < 2; ++m2)
#pragma unroll
          for (int g = 0; g < 3; ++g) {
            accN[m2][0][g] = MFMA(ah[m2], bh[0][g], accN[m2][0][g]);
            accN[m2][0][g] = MFMA(al[m2], bh[0][g], accN[m2][0][g]);
            accN[m2][0][g] = MFMA(ah[m2], bl[0][g], accN[m2][0][g]);
          }
      }
      if (gates) gate(m2u, ru, 0, rlu, e0);
      if (build) {
        // cluster t=1
#pragma unroll
        for (int m2 = 0; m2 < 2; ++m2)
#pragma unroll
          for (int g = 0; g < 3; ++g) {
            accN[m2][1][g] = MFMA(ah[m2], bh[1][g], accN[m2][1][g]);
            accN[m2][1][g] = MFMA(al[m2], bh[1][g], accN[m2][1][g]);
            accN[m2][1][g] = MFMA(ah[m2], bl[1][g], accN[m2][1][g]);
          }
      }
      if (gates) gate(m2u, ru, 1, rlu, e1);
    }

    if (gates) {
      // per-col-block 16-lane butterfly (identical tree to r4/r5)
#pragma unroll
      for (int m2 = 0; m2 < 2; ++m2)
#pragma unroll
        for (int r = 0; r < 4; ++r)
#pragma unroll
          for (int t = 0; t < 2; ++t) {
#pragma unroll
            for (int mask = 1; mask < 16; mask <<= 1)
              opart[m2][r][t] += __shfl_xor(opart[m2][r][t], mask, 16);
          }
      if (c16 == 0) {
#pragma unroll
        for (int m2 = 0; m2 < 2; ++m2)
#pragma unroll
          for (int r = 0; r < 4; ++r)
#pragma unroll
            for (int t = 0; t < 2; ++t)
              osc[(mtC0 + m2) * 16 + grp * 4 + r][2 * wv + t] = opart[m2][r][t];
      }
    }
  };

  // prologue: acc(R0, step 0); no gates, no finalize
  phase(accB, accA, h_reg0, 0, 0, 0, 0, true, false, false);

  for (int step = 0; step < kNOut; ++step) {
    // Phase A: finalize o/q(R1, step-1); gates R0(step) ; build acc(R1, step)
    phase(accA, accB, h_reg0, 0, 2, 32, step - 1, true, true, step > 0);
    __syncthreads();
    // Phase B: finalize o/q(R0, step); gates R1(step) ; build acc(R0, step+1)
    phase(accB, accA, h_reg1, 2, 0, 0, step, step < kNOut - 1, true, true);
    __syncthreads();
  }

  // epilogue: o/q(R1, 11) from osc written in the last phase B
  {
    float s = bo;
#pragma unroll
    for (int w2 = 0; w2 < 16; ++w2) s += osc[lane][w2];
    const float qn = s > 0.0f ? 1.0f : -1.0f;
    if (wv == 0 && lane >= 32) {
      const size_t gr = (size_t)(row0 + lane);
      out[gr * kNOut + (kNOut - 1)] = s;
      out[q_off + gr * kNOut + (kNOut - 1)] = qn;
    }
  }
}

extern "C" void kernel_launch(void* const* d_in, const int* in_sizes, int n_in,
                              void* d_out, int out_size, void* d_ws, size_t ws_size,
                              hipStream_t stream) {
  (void)in_sizes; (void)n_in; (void)out_size; (void)ws_size;
  const float* emb = (const float*)d_in[0];
  const float* w_ih = (const float*)d_in[1];
  const float* w_hh = (const float*)d_in[2];
  const float* b_ih = (const float*)d_in[3];
  const float* b_hh = (const float*)d_in[4];
  const float* w_out = (const float*)d_in[5];
  const float* b_out = (const float*)d_in[6];

  short* Bh = (short*)d_ws;                  // [768][256] bf16 hi
  short* Bl = Bh + kWhh;                     // [768][256] bf16 lo (768 KiB total)

  split_whh_kernel<<<kWhh / (256 * 4), 256, 0, stream>>>(w_hh, Bh, Bl);
  rbq_mfma5_kernel<<<kBL / kRows, kThreads, 0, stream>>>(
      emb, w_ih, b_ih, b_hh, w_out, b_out, Bh, Bl, (float*)d_out);
}